// Round 2
// baseline (458.300 us; speedup 1.0000x reference)
//
#include <hip/hip_runtime.h>

// DynamicRouting: votes [B=32, NIN=2048, NOUT=64, ATOMS=16] fp32, 3 routing iters.
// 3 streaming passes over votes (pose depends on a full n_in reduction, so 3
// reads are structural). Lane = out-capsule (64 lanes = 64 outs): softmax over
// outs is a 6-level shuffle butterfly (max-reduce dropped: |logit| <= ~14, exp
// can't overflow fp32). 4 rows batched per inner iter -> 4 independent shuffle
// chains + 16 loads in flight. 2048 blocks for latency hiding.

#define NB 32
#define NIN 2048
#define NOUT 64
#define ATOMS 16
#define EPSF 1e-9f

#define ROWS_PER_WAVE 8
#define WAVES_PER_BLOCK 4
#define ROWS_PER_BLOCK (ROWS_PER_WAVE * WAVES_PER_BLOCK) // 32
#define CHUNKS (NIN / ROWS_PER_BLOCK)                    // 64
#define RBATCH 4

template <int USE_POSE>
__global__ __launch_bounds__(256, 4) void route_pass(
    const float* __restrict__ votes,
    const float* __restrict__ pose_accum,
    float* __restrict__ preact)
{
    const int b     = blockIdx.x / CHUNKS;
    const int chunk = blockIdx.x % CHUNKS;
    const int wave  = threadIdx.x >> 6;
    const int lane  = threadIdx.x & 63; // = out-capsule index

    // pose fragment for this lane's out-capsule, in registers
    float pose[ATOMS];
    if (USE_POSE) {
        const float4* p4 = reinterpret_cast<const float4*>(pose_accum) + (b * NOUT + lane) * 4;
        float4 q0 = p4[0], q1 = p4[1], q2 = p4[2], q3 = p4[3];
        pose[0]=q0.x; pose[1]=q0.y; pose[2]=q0.z; pose[3]=q0.w;
        pose[4]=q1.x; pose[5]=q1.y; pose[6]=q1.z; pose[7]=q1.w;
        pose[8]=q2.x; pose[9]=q2.y; pose[10]=q2.z; pose[11]=q2.w;
        pose[12]=q3.x; pose[13]=q3.y; pose[14]=q3.z; pose[15]=q3.w;
    }

    float acc[ATOMS];
#pragma unroll
    for (int a = 0; a < ATOMS; ++a) acc[a] = 0.0f;

    const int in0 = chunk * ROWS_PER_BLOCK + wave * ROWS_PER_WAVE;
    const float4* vrow = reinterpret_cast<const float4*>(votes)
                       + ((size_t)(b * NIN + in0) * NOUT + lane) * (ATOMS / 4);

    for (int r0 = 0; r0 < ROWS_PER_WAVE; r0 += RBATCH) {
        // issue all loads for the batch first (16 x dwordx4 in flight)
        float4 c[RBATCH][4];
#pragma unroll
        for (int r = 0; r < RBATCH; ++r) {
            const float4* vp = vrow + (size_t)(r0 + r) * (NOUT * (ATOMS / 4));
            c[r][0] = vp[0]; c[r][1] = vp[1]; c[r][2] = vp[2]; c[r][3] = vp[3];
        }

        float cc[RBATCH];
        if (USE_POSE) {
            float s[RBATCH], e[RBATCH];
#pragma unroll
            for (int r = 0; r < RBATCH; ++r) {
                const float* v = reinterpret_cast<const float*>(&c[r][0]);
                float logit = 0.0f;
#pragma unroll
                for (int a = 0; a < ATOMS; ++a) logit = fmaf(v[a], pose[a], logit);
                // no max-subtraction: |logit| <= ||v||*||pose_accum|| << 80
                e[r] = __expf(logit);
                s[r] = e[r];
            }
            // 4 independent butterfly chains, interleaved per level
#pragma unroll
            for (int mask = 32; mask >= 1; mask >>= 1) {
#pragma unroll
                for (int r = 0; r < RBATCH; ++r)
                    s[r] += __shfl_xor(s[r], mask, 64);
            }
#pragma unroll
            for (int r = 0; r < RBATCH; ++r) cc[r] = e[r] / s[r];
        } else {
#pragma unroll
            for (int r = 0; r < RBATCH; ++r) cc[r] = 1.0f / 64.0f;
        }
#pragma unroll
        for (int r = 0; r < RBATCH; ++r) {
            const float* v = reinterpret_cast<const float*>(&c[r][0]);
#pragma unroll
            for (int a = 0; a < ATOMS; ++a) acc[a] = fmaf(cc[r], v[a], acc[a]);
        }
    }

    // block-level reduction across the 4 waves, then one atomicAdd set per block
    __shared__ float red[WAVES_PER_BLOCK * NOUT * ATOMS]; // 16 KiB
#pragma unroll
    for (int a = 0; a < ATOMS; ++a)
        red[(wave * NOUT + lane) * ATOMS + a] = acc[a];
    __syncthreads();

    for (int idx = threadIdx.x; idx < NOUT * ATOMS; idx += 256) {
        float t = red[idx] + red[NOUT * ATOMS + idx]
                + red[2 * NOUT * ATOMS + idx] + red[3 * NOUT * ATOMS + idx];
        atomicAdd(&preact[b * NOUT * ATOMS + idx], t);
    }
}

// mode 0: pose_accum = pose, zero preact ; mode 1: pose_accum += pose, zero preact ;
// mode 2: write d_out (pose + prob)
__global__ __launch_bounds__(256) void squash_k(
    const float* __restrict__ preact_in,
    float* __restrict__ preact_clr,
    float* __restrict__ pose_accum,
    float* __restrict__ d_out,
    int mode)
{
    int idx = blockIdx.x * 256 + threadIdx.x; // < NB*NOUT*ATOMS, 16 lanes per (b,out)
    float s = preact_in[idx];
    float sq = s * s;
#pragma unroll
    for (int mask = 1; mask < ATOMS; mask <<= 1)
        sq += __shfl_xor(sq, mask, 64);
    float norm = sqrtf(sq + EPSF);
    float f = (sq / (1.0f + sq)) / norm;
    float p = f * s;
    if (mode == 0) {
        pose_accum[idx] = p;
        preact_clr[idx] = 0.0f;
    } else if (mode == 1) {
        pose_accum[idx] += p;
        preact_clr[idx] = 0.0f;
    } else {
        d_out[idx] = p;
        if ((idx & (ATOMS - 1)) == 0) {
            float psq = f * f * sq; // sum over atoms of pose^2
            d_out[NB * NOUT * ATOMS + (idx >> 4)] = sqrtf(psq + EPSF);
        }
    }
}

extern "C" void kernel_launch(void* const* d_in, const int* in_sizes, int n_in,
                              void* d_out, int out_size, void* d_ws, size_t ws_size,
                              hipStream_t stream) {
    const float* votes = (const float*)d_in[0];
    float* out = (float*)d_out;

    float* preact     = (float*)d_ws;                 // 32768 floats
    float* pose_accum = preact + NB * NOUT * ATOMS;   // 32768 floats
    const size_t pre_bytes = (size_t)NB * NOUT * ATOMS * sizeof(float);

    dim3 blk(256);
    dim3 grid_route(NB * CHUNKS);                 // 2048 blocks
    dim3 grid_sq(NB * NOUT * ATOMS / 256);        // 128 blocks

    // d_ws is poisoned 0xAA before every call: zero preact once, squash_k
    // re-zeros it for subsequent iterations.
    hipMemsetAsync(preact, 0, pre_bytes, stream);

    // ---- iteration 0: c = 1/64 uniform ----
    route_pass<0><<<grid_route, blk, 0, stream>>>(votes, nullptr, preact);
    squash_k<<<grid_sq, blk, 0, stream>>>(preact, preact, pose_accum, nullptr, 0);

    // ---- iteration 1: logits = <votes, pose0> ----
    route_pass<1><<<grid_route, blk, 0, stream>>>(votes, pose_accum, preact);
    squash_k<<<grid_sq, blk, 0, stream>>>(preact, preact, pose_accum, nullptr, 1);

    // ---- iteration 2: logits = <votes, pose0+pose1> ----
    route_pass<1><<<grid_route, blk, 0, stream>>>(votes, pose_accum, preact);
    squash_k<<<grid_sq, blk, 0, stream>>>(preact, nullptr, nullptr, out, 2);
}